// Round 1
// baseline (6848.113 us; speedup 1.0000x reference)
//
#include <hip/hip_runtime.h>

// ---------------------------------------------------------------------------
// RWA recurrent cell, MI355X.
// B=32, T=128, F=128, NF=8, NC=1024, KW=5, NCLS=1000.
// Strategy: precompute XR = x @ Wx^T for all t (GEMM), then one cooperative
// kernel runs the 128-step scan with 2 grid barriers per step (conv -> BN
// stats -> elementwise). States n,d,a_max live in registers for all steps.
// ---------------------------------------------------------------------------

#define NB 256   // blocks in scan kernel (1 per CU)
#define NT 256   // threads per block

constexpr int Bb  = 32;
constexpr int Tt  = 128;
constexpr int Ff  = 128;
constexpr int NFc = 8;
constexpr int NCc = 1024;
constexpr int PROW = 1032;             // padded row: [4 zeros][1024 data][4 zeros]
constexpr float EPSf  = 1e-5f;
constexpr float INV_N = 1.0f / 32768.0f;   // 1/(B*NC)

// workspace layout (in floats)
constexpr size_t XR_OFF  = 0;                          // [T*B][PROW]
constexpr size_t XR_SZ   = (size_t)Tt * Bb * PROW;     // 4,227,072
constexpr size_t WT_OFF  = XR_OFF + XR_SZ;             // [F][NC] transposed resize w
constexpr size_t WT_SZ   = (size_t)Ff * NCc;           // 131,072
constexpr size_t HB_OFF  = WT_OFF + WT_SZ;             // [B][NF][PROW]
constexpr size_t HB_SZ   = (size_t)Bb * NFc * PROW;    // 264,192
constexpr size_t AC_OFF  = HB_OFF + HB_SZ;             // accum [2][8][8]
constexpr size_t BAR_OFF = AC_OFF + 128;               // 1024 u32 barrier area
// total ~ 4.62M floats ~ 18.5 MB

// output offsets (floats): (outs, s, n, d, h, a_max)
constexpr int OUT_S  = 32000;
constexpr int OUT_N  = 294144;
constexpr int OUT_D  = 556288;
constexpr int OUT_H  = 818432;
constexpr int OUT_AM = 1080576;

__device__ __forceinline__ float fast_tanh(float x) {
  float e = __expf(2.0f * x);
  return 1.0f - 2.0f / (e + 1.0f);
}

// two-level grid barrier: 16 groups of 16 blocks; counters 128B apart.
__device__ __forceinline__ void gbar(unsigned* bar, unsigned expected) {
  __syncthreads();
  if (threadIdx.x == 0) {
    unsigned* gcnt = bar + (blockIdx.x >> 4) * 32;
    unsigned* root = bar + 512;
    unsigned* gen  = bar + 544;
    bool last = false;
    if (__hip_atomic_fetch_add(gcnt, 1u, __ATOMIC_ACQ_REL, __HIP_MEMORY_SCOPE_AGENT) == 15u) {
      __hip_atomic_store(gcnt, 0u, __ATOMIC_RELAXED, __HIP_MEMORY_SCOPE_AGENT);
      if (__hip_atomic_fetch_add(root, 1u, __ATOMIC_ACQ_REL, __HIP_MEMORY_SCOPE_AGENT) == 15u) {
        __hip_atomic_store(root, 0u, __ATOMIC_RELAXED, __HIP_MEMORY_SCOPE_AGENT);
        __hip_atomic_store(gen, expected, __ATOMIC_RELEASE, __HIP_MEMORY_SCOPE_AGENT);
        last = true;
      }
    }
    if (!last) {
      while (__hip_atomic_load(gen, __ATOMIC_ACQUIRE, __HIP_MEMORY_SCOPE_AGENT) < expected) {
        __builtin_amdgcn_s_sleep(1);
      }
    }
  }
  __syncthreads();
}

// ---------------------------------------------------------------------------
// prep: transpose x_resize_w (1024x128 -> 128x1024), zero accum + barrier
// ---------------------------------------------------------------------------
__global__ void prep_kernel(const float* __restrict__ w, float* __restrict__ wT,
                            float* __restrict__ accum, unsigned* __restrict__ bar) {
  const int g = blockIdx.x * 256 + threadIdx.x;
  if (g < 131072) {
    const int c = g >> 7, k = g & 127;
    wT[k * 1024 + c] = w[g];
  }
  if (g < 128)  accum[g] = 0.0f;
  if (g < 1024) bar[g] = 0u;
}

// ---------------------------------------------------------------------------
// XR[t*B+b][c] = sum_k x[b][t][k] * wT[k][c], written into padded rows.
// 256 blocks x 256 threads; block handles 16 tb-rows, thread 4 columns.
// ---------------------------------------------------------------------------
__global__ void __launch_bounds__(256) xr_kernel(const float* __restrict__ x,
                                                 const float* __restrict__ wT,
                                                 float* __restrict__ XR) {
  const int tb0 = blockIdx.x * 16;
  const int c0  = threadIdx.x * 4;
  float4 acc[16];
#pragma unroll
  for (int j = 0; j < 16; ++j) acc[j] = make_float4(0.f, 0.f, 0.f, 0.f);

#pragma unroll 4
  for (int k = 0; k < 128; ++k) {
    const float4 wv = *(const float4*)(wT + (size_t)k * 1024 + c0);
#pragma unroll
    for (int j = 0; j < 16; ++j) {
      const int tb = tb0 + j;
      const float xs = x[(size_t)(tb & 31) * 16384 + (size_t)(tb >> 5) * 128 + k];
      acc[j].x = fmaf(xs, wv.x, acc[j].x);
      acc[j].y = fmaf(xs, wv.y, acc[j].y);
      acc[j].z = fmaf(xs, wv.z, acc[j].z);
      acc[j].w = fmaf(xs, wv.w, acc[j].w);
    }
  }
#pragma unroll
  for (int j = 0; j < 16; ++j) {
    float* row = XR + (size_t)(tb0 + j) * PROW;
    *(float4*)(row + 4 + c0) = acc[j];
    if (threadIdx.x == 0)   { row[0] = row[1] = row[2] = row[3] = 0.f; }
    if (threadIdx.x == 255) { row[1028] = row[1029] = row[1030] = row[1031] = 0.f; }
  }
}

// ---------------------------------------------------------------------------
// cooperative scan kernel: block = (b, f) pane, thread = 4 columns.
// ---------------------------------------------------------------------------
__global__ void __launch_bounds__(NT) scan_kernel(
    const float* __restrict__ XR, float* __restrict__ hbuf, float* accum,
    unsigned* bar,
    const float* __restrict__ s_in, const float* __restrict__ n_in,
    const float* __restrict__ d_in, const float* __restrict__ h_in,
    const float* __restrict__ am_in,
    const float* __restrict__ gw, const float* __restrict__ ggm, const float* __restrict__ gbt,
    const float* __restrict__ uw, const float* __restrict__ ugm, const float* __restrict__ ubt,
    const float* __restrict__ aw, const float* __restrict__ agm, const float* __restrict__ abt,
    const float* __restrict__ dw, const float* __restrict__ dgm, const float* __restrict__ dbt,
    float* __restrict__ out)
{
  const int bb  = (int)blockIdx.x >> 3;   // batch index
  const int f   = (int)blockIdx.x & 7;    // output channel
  const int tid = (int)threadIdx.x;
  const int c0  = tid * 4;
  const int cellbase = bb * (NFc * NCc) + f * NCc + c0;

  unsigned bexp = 0;
  __shared__ float red[4][8];

  // per-channel BN params (wave-uniform -> SGPRs)
  const float ggamma = ggm[f], gbeta = gbt[f];
  const float ugamma = ugm[f], ubeta = ubt[f];
  const float agamma = agm[f], abeta = abt[f];
  const float dgamma = dgm[f], dbeta = dbt[f];

  // states in registers for all 128 steps
  float nst[4], dst[4], amst[4], hv[4];
  {
    const float4 n4 = *(const float4*)(n_in + cellbase);
    const float4 d4 = *(const float4*)(d_in + cellbase);
    const float4 a4 = *(const float4*)(am_in + cellbase);
    const float4 h4 = *(const float4*)(h_in + cellbase);
    const float4 s4 = *(const float4*)(s_in + cellbase);
    nst[0] = n4.x; nst[1] = n4.y; nst[2] = n4.z; nst[3] = n4.w;
    dst[0] = d4.x; dst[1] = d4.y; dst[2] = d4.z; dst[3] = d4.w;
    amst[0] = a4.x; amst[1] = a4.y; amst[2] = a4.z; amst[3] = a4.w;
    hv[0] = h4.x + fast_tanh(s4.x);
    hv[1] = h4.y + fast_tanh(s4.y);
    hv[2] = h4.z + fast_tanh(s4.z);
    hv[3] = h4.w + fast_tanh(s4.w);
    float* hp = hbuf + (size_t)bb * (NFc * PROW) + (size_t)f * PROW;
    *(float4*)(hp + 4 + c0) = make_float4(hv[0], hv[1], hv[2], hv[3]);
    if (tid == 0) {
      hp[0] = hp[1] = hp[2] = hp[3] = 0.f;
      hp[1028] = hp[1029] = hp[1030] = hp[1031] = 0.f;
    }
  }
  gbar(bar, ++bexp);

  for (int t = 0; t < Tt; ++t) {
    const int par = t & 1;

    // ---- phase A: raw convs -------------------------------------------------
    float gr[4]  = {0.f, 0.f, 0.f, 0.f};
    float ar2[4] = {0.f, 0.f, 0.f, 0.f};
    float dr[4]  = {0.f, 0.f, 0.f, 0.f};
    float ur[4]  = {0.f, 0.f, 0.f, 0.f};
    {
      const float* hrow  = hbuf + (size_t)bb * (NFc * PROW);
      const float* xrrow = XR + (size_t)(t * Bb + bb) * PROW;
#pragma unroll
      for (int ci = 0; ci < 9; ++ci) {
        const float* src = (ci == 0) ? xrrow : (hrow + (size_t)(ci - 1) * PROW);
        const float4 q0 = *(const float4*)(src + c0);
        const float4 q1 = *(const float4*)(src + c0 + 4);
        const float4 q2 = *(const float4*)(src + c0 + 8);
        const float w12[12] = {q0.x, q0.y, q0.z, q0.w, q1.x, q1.y, q1.z, q1.w,
                               q2.x, q2.y, q2.z, q2.w};
        const float* wgp = gw + (f * 9 + ci) * 5;
        const float* wap = aw + (f * 9 + ci) * 5;
        const float* wdp = dw + (f * 9 + ci) * 5;
#pragma unroll
        for (int kw = 0; kw < 5; ++kw) {
          const float wgv = wgp[kw], wav = wap[kw], wdv = wdp[kw];
#pragma unroll
          for (int j = 0; j < 4; ++j) {
            const float v = w12[2 + j + kw];
            gr[j]  = fmaf(v, wgv, gr[j]);
            ar2[j] = fmaf(v, wav, ar2[j]);
            dr[j]  = fmaf(v, wdv, dr[j]);
          }
        }
        if (ci == 0) {
#pragma unroll
          for (int kw = 0; kw < 5; ++kw) {
            const float wuv = uw[f * 5 + kw];
#pragma unroll
            for (int j = 0; j < 4; ++j)
              ur[j] = fmaf(w12[2 + j + kw], wuv, ur[j]);
          }
        }
      }
    }

    // ---- BN partial sums -> block reduce -> global atomics ------------------
    float ps[8];
    ps[0] = (gr[0] + gr[1]) + (gr[2] + gr[3]);
    ps[1] = (gr[0] * gr[0] + gr[1] * gr[1]) + (gr[2] * gr[2] + gr[3] * gr[3]);
    ps[2] = (ar2[0] + ar2[1]) + (ar2[2] + ar2[3]);
    ps[3] = (ar2[0] * ar2[0] + ar2[1] * ar2[1]) + (ar2[2] * ar2[2] + ar2[3] * ar2[3]);
    ps[4] = (dr[0] + dr[1]) + (dr[2] + dr[3]);
    ps[5] = (dr[0] * dr[0] + dr[1] * dr[1]) + (dr[2] * dr[2] + dr[3] * dr[3]);
    ps[6] = (ur[0] + ur[1]) + (ur[2] + ur[3]);
    ps[7] = (ur[0] * ur[0] + ur[1] * ur[1]) + (ur[2] * ur[2] + ur[3] * ur[3]);
#pragma unroll
    for (int k = 0; k < 8; ++k) {
      float v = ps[k];
#pragma unroll
      for (int m = 32; m >= 1; m >>= 1) v += __shfl_xor(v, m);
      if ((tid & 63) == 0) red[tid >> 6][k] = v;
    }
    __syncthreads();
    if (tid < 8) {
      const float v = (red[0][tid] + red[1][tid]) + (red[2][tid] + red[3][tid]);
      atomicAdd(accum + par * 64 + tid * 8 + f, v);
    }
    gbar(bar, ++bexp);

    // ---- phase B: BN + elementwise state update -----------------------------
    float st[8];
#pragma unroll
    for (int k = 0; k < 8; ++k)
      st[k] = __hip_atomic_load(accum + par * 64 + k * 8 + f,
                                __ATOMIC_RELAXED, __HIP_MEMORY_SCOPE_AGENT);
    const float mg = st[0] * INV_N; const float vg = fmaf(-mg, mg, st[1] * INV_N);
    const float sg = ggamma * rsqrtf(vg + EPSf); const float og = fmaf(-mg, sg, gbeta);
    const float ma = st[2] * INV_N; const float va = fmaf(-ma, ma, st[3] * INV_N);
    const float sa = agamma * rsqrtf(va + EPSf); const float oa = fmaf(-ma, sa, abeta);
    const float md = st[4] * INV_N; const float vd = fmaf(-md, md, st[5] * INV_N);
    const float sd = dgamma * rsqrtf(vd + EPSf); const float od = fmaf(-md, sd, dbeta);
    const float mu = st[6] * INV_N; const float vu = fmaf(-mu, mu, st[7] * INV_N);
    const float su = ugamma * rsqrtf(vu + EPSf); const float ou = fmaf(-mu, su, ubeta);

#pragma unroll
    for (int j = 0; j < 4; ++j) {
      const float gb = fmaf(gr[j], sg, og);
      const float ab = fmaf(ar2[j], sa, oa);
      const float db = fmaf(dr[j], sd, od);
      const float ub = fmaf(ur[j], su, ou);
      const float dec = 1.0f / (1.0f + __expf(-db));   // sigmoid
      const float ed  = __expf(-dec);
      const float z   = ub * fast_tanh(gb);
      const float anew = fmaxf(amst[j] * ed, ab);
      const float e1 = __expf(amst[j] - anew);
      const float e2 = __expf(ab - anew);
      const float ede1 = ed * e1;
      nst[j] = fmaf(nst[j], ede1, z * e2);
      dst[j] = fmaf(dst[j], ede1, e2);
      amst[j] = anew;
      hv[j] = fast_tanh(nst[j] / dst[j]);
    }
    {
      float* hp = hbuf + (size_t)bb * (NFc * PROW) + (size_t)f * PROW;
      *(float4*)(hp + 4 + c0) = make_float4(hv[0], hv[1], hv[2], hv[3]);
    }
    // zero next-parity accumulators (safe: last read 2 barriers ago)
    if (blockIdx.x == 0 && tid < 64)
      __hip_atomic_store(accum + ((par ^ 1) * 64) + tid, 0.0f,
                         __ATOMIC_RELAXED, __HIP_MEMORY_SCOPE_AGENT);
    gbar(bar, ++bexp);
  }

  // ---- final outputs --------------------------------------------------------
  {
    const float4 s4 = *(const float4*)(s_in + cellbase);
    *(float4*)(out + OUT_S  + cellbase) = s4;
    *(float4*)(out + OUT_N  + cellbase) = make_float4(nst[0], nst[1], nst[2], nst[3]);
    *(float4*)(out + OUT_D  + cellbase) = make_float4(dst[0], dst[1], dst[2], dst[3]);
    *(float4*)(out + OUT_H  + cellbase) = make_float4(hv[0], hv[1], hv[2], hv[3]);
    *(float4*)(out + OUT_AM + cellbase) = make_float4(amst[0], amst[1], amst[2], amst[3]);
  }
}

// ---------------------------------------------------------------------------
// outs[b][o] = dot(h_flat[b], o_w[o]) + o_b[o]
// ---------------------------------------------------------------------------
__global__ void __launch_bounds__(256) out_kernel(const float* __restrict__ hbuf,
                                                  const float* __restrict__ ow,
                                                  const float* __restrict__ ob,
                                                  float* __restrict__ out) {
  const int g = blockIdx.x * 256 + threadIdx.x;  // 32000 threads
  const int o = g >> 5;
  const int b = g & 31;
  const float* hp = hbuf + (size_t)b * (NFc * PROW);
  const float* wp = ow + (size_t)o * 8192;
  float acc = 0.f;
#pragma unroll
  for (int f2 = 0; f2 < 8; ++f2) {
    const float* h2 = hp + (size_t)f2 * PROW + 4;
    const float* w2 = wp + (size_t)f2 * 1024;
#pragma unroll 8
    for (int c = 0; c < 1024; c += 4) {
      const float4 hv4 = *(const float4*)(h2 + c);
      const float4 wv4 = *(const float4*)(w2 + c);
      acc = fmaf(hv4.x, wv4.x, acc);
      acc = fmaf(hv4.y, wv4.y, acc);
      acc = fmaf(hv4.z, wv4.z, acc);
      acc = fmaf(hv4.w, wv4.w, acc);
    }
  }
  out[b * 1000 + o] = acc + ob[o];
}

// ---------------------------------------------------------------------------
extern "C" void kernel_launch(void* const* d_in, const int* in_sizes, int n_in,
                              void* d_out, int out_size, void* d_ws, size_t ws_size,
                              hipStream_t stream) {
  (void)in_sizes; (void)n_in; (void)out_size; (void)ws_size;
  const float* x   = (const float*)d_in[0];
  const float* s   = (const float*)d_in[1];
  const float* n_  = (const float*)d_in[2];
  const float* dd  = (const float*)d_in[3];
  const float* h   = (const float*)d_in[4];
  const float* am  = (const float*)d_in[5];
  const float* xrw = (const float*)d_in[6];
  const float* gw  = (const float*)d_in[7];
  const float* ggm = (const float*)d_in[9];
  const float* gbt = (const float*)d_in[10];
  const float* uw  = (const float*)d_in[11];
  const float* ugm = (const float*)d_in[13];
  const float* ubt = (const float*)d_in[14];
  const float* aw  = (const float*)d_in[15];
  const float* agm = (const float*)d_in[17];
  const float* abt = (const float*)d_in[18];
  const float* dw  = (const float*)d_in[19];
  const float* dgm = (const float*)d_in[21];
  const float* dbt = (const float*)d_in[22];
  const float* ow  = (const float*)d_in[23];
  const float* ob  = (const float*)d_in[24];
  float* out = (float*)d_out;
  float* ws  = (float*)d_ws;

  float* XR    = ws + XR_OFF;
  float* wT    = ws + WT_OFF;
  float* hbuf  = ws + HB_OFF;
  float* accum = ws + AC_OFF;
  unsigned* bar = (unsigned*)(ws + BAR_OFF);

  prep_kernel<<<dim3(512), dim3(256), 0, stream>>>(xrw, wT, accum, bar);
  xr_kernel<<<dim3(256), dim3(256), 0, stream>>>(x, wT, XR);

  void* args[] = { &XR, &hbuf, &accum, &bar, &s, &n_, &dd, &h, &am,
                   &gw, &ggm, &gbt, &uw, &ugm, &ubt,
                   &aw, &agm, &abt, &dw, &dgm, &dbt, &out };
  hipError_t err = hipLaunchCooperativeKernel((void*)scan_kernel, dim3(NB), dim3(NT),
                                              args, 0, stream);
  if (err != hipSuccess) {
    // fallback: plain launch (grid trivially co-resident: 1 block/CU)
    scan_kernel<<<dim3(NB), dim3(NT), 0, stream>>>(XR, hbuf, accum, bar, s, n_, dd, h, am,
                                                   gw, ggm, gbt, uw, ugm, ubt,
                                                   aw, agm, abt, dw, dgm, dbt, out);
  }

  out_kernel<<<dim3(125), dim3(256), 0, stream>>>(hbuf, ow, ob, out);
}

// Round 2
// 2778.383 us; speedup vs baseline: 2.4648x; 2.4648x over previous
//
#include <hip/hip_runtime.h>

// ---------------------------------------------------------------------------
// RWA recurrent cell, MI355X — round 2.
// Decompose by batch only: 32 blocks x 512 threads. h lives in LDS (never
// crosses blocks). Only cross-block data: 64 BN-stat floats/step, exchanged
// via relaxed agent-scope atomics (slot per block) + one monotonic counter.
// No grid barrier, no L2 writeback/invalidate per step.
// ---------------------------------------------------------------------------

#define NBLK 32
#define NTHR 512

constexpr int Bb = 32, Tt = 128, NFc = 8, NCc = 1024;
constexpr int PROW = 1032;   // padded XR row: [4 pad][1024][4 pad]
constexpr int HROW = 1056;   // padded LDS h row (floats) = 264 x 16B chunks
constexpr float EPSf  = 1e-5f;
constexpr float INV_N = 1.0f / 32768.0f;   // 1/(B*NC)

// workspace layout (floats)
constexpr size_t XR_OFF  = 0;
constexpr size_t XR_SZ   = (size_t)Tt * Bb * PROW;     // 4,227,072
constexpr size_t WT_OFF  = XR_OFF + XR_SZ;             // [128][1024] W^T
constexpr size_t WT_SZ   = 131072;
constexpr size_t WPK_OFF = WT_OFF + WT_SZ;             // [8][10][16] packed conv w
constexpr size_t WPK_SZ  = 1280;
constexpr size_t SL_OFF  = WPK_OFF + WPK_SZ;           // stats slots [2][32][64]
constexpr size_t SL_SZ   = 4096;
constexpr size_t CNT_OFF = SL_OFF + SL_SZ;             // 16 u32 counter area

// output offsets (floats): (outs, s, n, d, h, a_max)
constexpr int OUT_S  = 32000;
constexpr int OUT_N  = 294144;
constexpr int OUT_D  = 556288;
constexpr int OUT_H  = 818432;
constexpr int OUT_AM = 1080576;

__device__ __forceinline__ int swz(int m) { return m ^ ((m >> 3) & 7); }

__device__ __forceinline__ float fast_tanh(float x) {
  float e = __expf(2.0f * x);
  return 1.0f - 2.0f / (e + 1.0f);
}

// ---------------------------------------------------------------------------
// prep: transpose x_resize_w, pack conv weights [f][ci][16]=(g5,a5,d5,pad)
// with row ci=9 holding u5; zero the counter.
// ---------------------------------------------------------------------------
__global__ void prep_kernel(const float* __restrict__ w, float* __restrict__ wT,
                            const float* __restrict__ gw, const float* __restrict__ aw,
                            const float* __restrict__ dw, const float* __restrict__ uw,
                            float* __restrict__ wpack, unsigned* __restrict__ cnt) {
  const int g = blockIdx.x * 256 + threadIdx.x;
  if (g < 131072) {
    const int c = g >> 7, k = g & 127;
    wT[k * 1024 + c] = w[g];
  }
  if (g < 1280) {
    const int f = g / 160, r = g % 160, ci = r >> 4, k = r & 15;
    float v = 0.f;
    if (ci < 9) {
      if (k < 5)       v = gw[(f * 9 + ci) * 5 + k];
      else if (k < 10) v = aw[(f * 9 + ci) * 5 + (k - 5)];
      else if (k < 15) v = dw[(f * 9 + ci) * 5 + (k - 10)];
    } else {
      if (k < 5)       v = uw[f * 5 + k];
    }
    wpack[g] = v;
  }
  if (g < 16) cnt[g] = 0u;
}

// ---------------------------------------------------------------------------
// XR[t*B+b][c] = sum_k x[b][t][k] * wT[k][c], into padded rows.
// ---------------------------------------------------------------------------
__global__ void __launch_bounds__(256) xr_kernel(const float* __restrict__ x,
                                                 const float* __restrict__ wT,
                                                 float* __restrict__ XR) {
  const int tb0 = blockIdx.x * 16;
  const int c0  = threadIdx.x * 4;
  float4 acc[16];
#pragma unroll
  for (int j = 0; j < 16; ++j) acc[j] = make_float4(0.f, 0.f, 0.f, 0.f);
#pragma unroll 4
  for (int k = 0; k < 128; ++k) {
    const float4 wv = *(const float4*)(wT + (size_t)k * 1024 + c0);
#pragma unroll
    for (int j = 0; j < 16; ++j) {
      const int tb = tb0 + j;
      const float xs = x[(size_t)(tb & 31) * 16384 + (size_t)(tb >> 5) * 128 + k];
      acc[j].x = fmaf(xs, wv.x, acc[j].x);
      acc[j].y = fmaf(xs, wv.y, acc[j].y);
      acc[j].z = fmaf(xs, wv.z, acc[j].z);
      acc[j].w = fmaf(xs, wv.w, acc[j].w);
    }
  }
#pragma unroll
  for (int j = 0; j < 16; ++j) {
    float* row = XR + (size_t)(tb0 + j) * PROW;
    *(float4*)(row + 4 + c0) = acc[j];
    if (threadIdx.x == 0)   { row[0] = row[1] = row[2] = row[3] = 0.f; }
    if (threadIdx.x == 255) { row[1028] = row[1029] = row[1030] = row[1031] = 0.f; }
  }
}

// ---------------------------------------------------------------------------
// scan kernel: block = batch bb; wave w = feature channel f; lane = 16 cols.
// ---------------------------------------------------------------------------
__global__ void __launch_bounds__(NTHR, 2) scan_kernel(
    const float* __restrict__ XR, const float* __restrict__ wpack,
    float* slots, unsigned* cnt,
    const float* __restrict__ s_in, const float* __restrict__ n_in,
    const float* __restrict__ d_in, const float* __restrict__ h_in,
    const float* __restrict__ am_in,
    const float* __restrict__ ggm, const float* __restrict__ gbt,
    const float* __restrict__ ugm, const float* __restrict__ ubt,
    const float* __restrict__ agm, const float* __restrict__ abt,
    const float* __restrict__ dgm, const float* __restrict__ dbt,
    float* __restrict__ out)
{
  const int bb   = (int)blockIdx.x;
  const int tid  = (int)threadIdx.x;
  const int w    = tid >> 6;          // wave index == feature channel f
  const int lane = tid & 63;
  const int fu   = __builtin_amdgcn_readfirstlane(w);   // uniform f -> SGPR
  const float* __restrict__ wpk = wpack + fu * 160;     // [ci][16]
  const int cellbase = bb * 8192 + w * 1024 + lane * 16;

  const float ggamma = ggm[fu], gbeta = gbt[fu];
  const float ugamma = ugm[fu], ubeta = ubt[fu];
  const float agamma = agm[fu], abeta = abt[fu];
  const float dgamma = dgm[fu], dbeta = dbt[fu];

  __shared__ float hl[8][HROW];       // 33 KB, chunk-swizzled rows

  // states in registers for all 128 steps
  float nst[16], dst[16], amst[16];
  {
#pragma unroll
    for (int q = 0; q < 4; ++q) {
      const float4 n4 = *(const float4*)(n_in  + cellbase + 4 * q);
      const float4 d4 = *(const float4*)(d_in  + cellbase + 4 * q);
      const float4 a4 = *(const float4*)(am_in + cellbase + 4 * q);
      const float4 h4 = *(const float4*)(h_in  + cellbase + 4 * q);
      const float4 s4 = *(const float4*)(s_in  + cellbase + 4 * q);
      nst[4*q+0] = n4.x; nst[4*q+1] = n4.y; nst[4*q+2] = n4.z; nst[4*q+3] = n4.w;
      dst[4*q+0] = d4.x; dst[4*q+1] = d4.y; dst[4*q+2] = d4.z; dst[4*q+3] = d4.w;
      amst[4*q+0] = a4.x; amst[4*q+1] = a4.y; amst[4*q+2] = a4.z; amst[4*q+3] = a4.w;
      float4 hv4;
      hv4.x = h4.x + fast_tanh(s4.x);
      hv4.y = h4.y + fast_tanh(s4.y);
      hv4.z = h4.z + fast_tanh(s4.z);
      hv4.w = h4.w + fast_tanh(s4.w);
      ((float4*)hl[w])[swz(4 * lane + 1 + q)] = hv4;
    }
    if (tid < 8) {  // zero pads: chunk 0 (cols -4..-1) and chunk 257 (1024..1027)
      const float4 z4 = make_float4(0.f, 0.f, 0.f, 0.f);
      ((float4*)hl[tid])[swz(0)]   = z4;
      ((float4*)hl[tid])[swz(257)] = z4;
    }
  }
  __syncthreads();

  for (int t = 0; t < Tt; ++t) {
    const int p = t & 1;

    // ---- phase A: raw convs (f32 VALU, weights via SGPR) -------------------
    float accg[16], acca[16], accd[16], accu[16];
#pragma unroll
    for (int j = 0; j < 16; ++j) { accg[j] = 0.f; acca[j] = 0.f; accd[j] = 0.f; accu[j] = 0.f; }

    const float4* __restrict__ xq = (const float4*)(XR + (size_t)(t * Bb + bb) * PROW);
#pragma unroll
    for (int ci = 0; ci < 9; ++ci) {
      float w24[24];
      if (ci == 0) {
#pragma unroll
        for (int k = 0; k < 6; ++k) {
          const float4 q = xq[4 * lane + k];
          w24[4*k+0] = q.x; w24[4*k+1] = q.y; w24[4*k+2] = q.z; w24[4*k+3] = q.w;
        }
      } else {
        const float4* rq = (const float4*)hl[ci - 1];
#pragma unroll
        for (int k = 0; k < 6; ++k) {
          const float4 q = rq[swz(4 * lane + k)];
          w24[4*k+0] = q.x; w24[4*k+1] = q.y; w24[4*k+2] = q.z; w24[4*k+3] = q.w;
        }
      }
      const float* wp = wpk + ci * 16;   // uniform -> s_load
#pragma unroll
      for (int kw = 0; kw < 5; ++kw) {
        const float wgv = wp[kw], wav = wp[5 + kw], wdv = wp[10 + kw];
#pragma unroll
        for (int j = 0; j < 16; ++j) {
          const float v = w24[j + kw + 2];
          accg[j] = fmaf(v, wgv, accg[j]);
          acca[j] = fmaf(v, wav, acca[j]);
          accd[j] = fmaf(v, wdv, accd[j]);
        }
      }
      if (ci == 0) {
        const float* wu = wpk + 144;     // u-conv taps
#pragma unroll
        for (int kw = 0; kw < 5; ++kw) {
          const float wuv = wu[kw];
#pragma unroll
          for (int j = 0; j < 16; ++j)
            accu[j] = fmaf(w24[j + kw + 2], wuv, accu[j]);
        }
      }
    }

    // ---- BN partial sums: wave reduce (f == wave) --------------------------
    float ps[8];
    {
      float sg_ = 0.f, qg_ = 0.f, sa_ = 0.f, qa_ = 0.f, sd_ = 0.f, qd_ = 0.f, su_ = 0.f, qu_ = 0.f;
#pragma unroll
      for (int j = 0; j < 16; ++j) {
        sg_ += accg[j]; qg_ = fmaf(accg[j], accg[j], qg_);
        sa_ += acca[j]; qa_ = fmaf(acca[j], acca[j], qa_);
        sd_ += accd[j]; qd_ = fmaf(accd[j], accd[j], qd_);
        su_ += accu[j]; qu_ = fmaf(accu[j], accu[j], qu_);
      }
      ps[0] = sg_; ps[1] = qg_; ps[2] = sa_; ps[3] = qa_;
      ps[4] = sd_; ps[5] = qd_; ps[6] = su_; ps[7] = qu_;
    }
#pragma unroll
    for (int k = 0; k < 8; ++k) {
#pragma unroll
      for (int m = 32; m >= 1; m >>= 1) ps[k] += __shfl_xor(ps[k], m);
    }
    if (lane == 0) {
      float* slot = slots + p * 2048 + bb * 64 + (w << 3);
#pragma unroll
      for (int k = 0; k < 8; ++k)
        __hip_atomic_store(slot + k, ps[k], __ATOMIC_RELAXED, __HIP_MEMORY_SCOPE_AGENT);
    }
    asm volatile("s_waitcnt vmcnt(0)" ::: "memory");
    __syncthreads();
    if (tid == 0) {
      __hip_atomic_fetch_add(cnt, 1u, __ATOMIC_RELAXED, __HIP_MEMORY_SCOPE_AGENT);
      const unsigned tgt = 32u * (unsigned)(t + 1);
      while (__hip_atomic_load(cnt, __ATOMIC_RELAXED, __HIP_MEMORY_SCOPE_AGENT) < tgt)
        __builtin_amdgcn_s_sleep(1);
    }
    __syncthreads();

    // ---- readback: sum 32 block-partials for this wave's f -----------------
    float st[8];
    {
      const int kk = lane & 7;
      const int b0 = lane >> 3;
      float v = 0.f;
#pragma unroll
      for (int q = 0; q < 4; ++q)
        v += __hip_atomic_load(slots + p * 2048 + (b0 + 8 * q) * 64 + (w << 3) + kk,
                               __ATOMIC_RELAXED, __HIP_MEMORY_SCOPE_AGENT);
      v += __shfl_xor(v, 8); v += __shfl_xor(v, 16); v += __shfl_xor(v, 32);
#pragma unroll
      for (int k = 0; k < 8; ++k) st[k] = __shfl(v, k);
    }
    const float mg = st[0] * INV_N; const float vg = fmaf(-mg, mg, st[1] * INV_N);
    const float sg = ggamma * rsqrtf(vg + EPSf); const float og = fmaf(-mg, sg, gbeta);
    const float ma = st[2] * INV_N; const float va = fmaf(-ma, ma, st[3] * INV_N);
    const float sa = agamma * rsqrtf(va + EPSf); const float oa = fmaf(-ma, sa, abeta);
    const float md = st[4] * INV_N; const float vd = fmaf(-md, md, st[5] * INV_N);
    const float sd = dgamma * rsqrtf(vd + EPSf); const float od = fmaf(-md, sd, dbeta);
    const float mu = st[6] * INV_N; const float vu = fmaf(-mu, mu, st[7] * INV_N);
    const float su = ugamma * rsqrtf(vu + EPSf); const float ou = fmaf(-mu, su, ubeta);

    // ---- phase B: BN + elementwise update ----------------------------------
    float hv[16];
#pragma unroll
    for (int j = 0; j < 16; ++j) {
      const float gb = fmaf(accg[j], sg, og);
      const float ab = fmaf(acca[j], sa, oa);
      const float db = fmaf(accd[j], sd, od);
      const float ub = fmaf(accu[j], su, ou);
      const float dec = 1.0f / (1.0f + __expf(-db));
      const float ed  = __expf(-dec);
      const float z   = ub * fast_tanh(gb);
      const float anew = fmaxf(amst[j] * ed, ab);
      const float e1 = __expf(amst[j] - anew);
      const float e2 = __expf(ab - anew);
      const float ede1 = ed * e1;
      nst[j]  = fmaf(nst[j], ede1, z * e2);
      dst[j]  = fmaf(dst[j], ede1, e2);
      amst[j] = anew;
      hv[j]   = fast_tanh(nst[j] / dst[j]);
    }
#pragma unroll
    for (int q = 0; q < 4; ++q)
      ((float4*)hl[w])[swz(4 * lane + 1 + q)] =
          make_float4(hv[4*q+0], hv[4*q+1], hv[4*q+2], hv[4*q+3]);
    __syncthreads();
  }

  // ---- final outputs --------------------------------------------------------
#pragma unroll
  for (int q = 0; q < 4; ++q) {
    const float4 s4 = *(const float4*)(s_in + cellbase + 4 * q);
    *(float4*)(out + OUT_S  + cellbase + 4 * q) = s4;
    *(float4*)(out + OUT_N  + cellbase + 4 * q) =
        make_float4(nst[4*q+0], nst[4*q+1], nst[4*q+2], nst[4*q+3]);
    *(float4*)(out + OUT_D  + cellbase + 4 * q) =
        make_float4(dst[4*q+0], dst[4*q+1], dst[4*q+2], dst[4*q+3]);
    *(float4*)(out + OUT_AM + cellbase + 4 * q) =
        make_float4(amst[4*q+0], amst[4*q+1], amst[4*q+2], amst[4*q+3]);
    *(float4*)(out + OUT_H  + cellbase + 4 * q) = ((float4*)hl[w])[swz(4 * lane + 1 + q)];
  }
}

// ---------------------------------------------------------------------------
// outs[b][o] = dot(h_flat[b], o_w[o]) + o_b[o]; h read from out+OUT_H.
// ---------------------------------------------------------------------------
__global__ void __launch_bounds__(256) out_kernel(const float* __restrict__ outH,
                                                  const float* __restrict__ ow,
                                                  const float* __restrict__ ob,
                                                  float* __restrict__ out) {
  const int g = blockIdx.x * 256 + threadIdx.x;  // 32000 threads
  const int o = g >> 5;
  const int b = g & 31;
  const float* hp = outH + (size_t)b * 8192;
  const float* wp = ow + (size_t)o * 8192;
  float acc = 0.f;
#pragma unroll 8
  for (int c = 0; c < 8192; c += 4) {
    const float4 hv4 = *(const float4*)(hp + c);
    const float4 wv4 = *(const float4*)(wp + c);
    acc = fmaf(hv4.x, wv4.x, acc);
    acc = fmaf(hv4.y, wv4.y, acc);
    acc = fmaf(hv4.z, wv4.z, acc);
    acc = fmaf(hv4.w, wv4.w, acc);
  }
  out[b * 1000 + o] = acc + ob[o];
}

// ---------------------------------------------------------------------------
extern "C" void kernel_launch(void* const* d_in, const int* in_sizes, int n_in,
                              void* d_out, int out_size, void* d_ws, size_t ws_size,
                              hipStream_t stream) {
  (void)in_sizes; (void)n_in; (void)out_size; (void)ws_size;
  const float* x   = (const float*)d_in[0];
  const float* s   = (const float*)d_in[1];
  const float* n_  = (const float*)d_in[2];
  const float* dd  = (const float*)d_in[3];
  const float* h   = (const float*)d_in[4];
  const float* am  = (const float*)d_in[5];
  const float* xrw = (const float*)d_in[6];
  const float* gw  = (const float*)d_in[7];
  const float* ggm = (const float*)d_in[9];
  const float* gbt = (const float*)d_in[10];
  const float* uw  = (const float*)d_in[11];
  const float* ugm = (const float*)d_in[13];
  const float* ubt = (const float*)d_in[14];
  const float* aw  = (const float*)d_in[15];
  const float* agm = (const float*)d_in[17];
  const float* abt = (const float*)d_in[18];
  const float* dw  = (const float*)d_in[19];
  const float* dgm = (const float*)d_in[21];
  const float* dbt = (const float*)d_in[22];
  const float* ow  = (const float*)d_in[23];
  const float* ob  = (const float*)d_in[24];
  float* out = (float*)d_out;
  float* ws  = (float*)d_ws;

  float* XR     = ws + XR_OFF;
  float* wT     = ws + WT_OFF;
  float* wpack  = ws + WPK_OFF;
  float* slots  = ws + SL_OFF;
  unsigned* cnt = (unsigned*)(ws + CNT_OFF);

  prep_kernel<<<dim3(512), dim3(256), 0, stream>>>(xrw, wT, gw, aw, dw, uw, wpack, cnt);
  xr_kernel<<<dim3(256), dim3(256), 0, stream>>>(x, wT, XR);

  void* args[] = { &XR, &wpack, &slots, &cnt, &s, &n_, &dd, &h, &am,
                   &ggm, &gbt, &ugm, &ubt, &agm, &abt, &dgm, &dbt, &out };
  hipError_t err = hipLaunchCooperativeKernel((void*)scan_kernel, dim3(NBLK), dim3(NTHR),
                                              args, 0, stream);
  if (err != hipSuccess) {
    scan_kernel<<<dim3(NBLK), dim3(NTHR), 0, stream>>>(XR, wpack, slots, cnt, s, n_, dd, h, am,
                                                       ggm, gbt, ugm, ubt, agm, abt, dgm, dbt, out);
  }

  out_kernel<<<dim3(125), dim3(256), 0, stream>>>(out + OUT_H, ow, ob, out);
}

// Round 3
// 1459.476 us; speedup vs baseline: 4.6922x; 1.9037x over previous
//
#include <hip/hip_runtime.h>

// ---------------------------------------------------------------------------
// RWA recurrent cell, MI355X — round 3.
// 256 blocks = 32 batches x 8 column-chunks (128 cols each), 512 threads
// (8 waves = 8 features, lane = 2 cols). h is block-local in LDS.
// ONE global sync per step:
//   pre-sync:  conv over own cols; atomicAdd BN partials (4-replica, padded);
//              export raw conv outputs at the 2 boundary cols per side.
//   post-sync: read stats; BN+state update for own cols AND 2 replicated
//              halo cols per side (using neighbor's exported conv outputs).
// ---------------------------------------------------------------------------

#define NBLK 256
#define NTHR 512

constexpr int Bb = 32, Tt = 128, NCc = 1024;
constexpr int PROW = 1032;       // padded XR row: [4 zeros][1024][4 zeros]
constexpr float EPSf  = 1e-5f;
constexpr float INV_N = 1.0f / 32768.0f;   // 1/(B*NC)

// workspace layout (floats)
constexpr size_t XR_OFF  = 0;
constexpr size_t XR_SZ   = (size_t)Tt * Bb * PROW;     // 4,227,072
constexpr size_t WT_OFF  = XR_OFF + XR_SZ;
constexpr size_t WT_SZ   = 131072;                     // [128][1024] W^T
constexpr size_t WPK_OFF = WT_OFF + WT_SZ;
constexpr size_t WPK_SZ  = 1280;                       // [8][10][16] packed conv w
constexpr size_t ACC_OFF = WPK_OFF + WPK_SZ;           // [3 par][4 rep][64][32]
constexpr size_t ACC_SZ  = 3 * 4 * 64 * 32;            // 24,576
constexpr size_t SL2_OFF = ACC_OFF + ACC_SZ;           // [2 par][32 bb][8 cc][2 side][64]
constexpr size_t SL2_SZ  = 2 * 32 * 8 * 2 * 64;        // 65,536
constexpr size_t CNT_OFF = SL2_OFF + SL2_SZ;           // 1024 u32 (leaf/root/gen, padded)

// output offsets (floats): (outs, s, n, d, h, a_max)
constexpr int OUT_S  = 32000;
constexpr int OUT_N  = 294144;
constexpr int OUT_D  = 556288;
constexpr int OUT_H  = 818432;
constexpr int OUT_AM = 1080576;

__device__ __forceinline__ float fast_tanh(float x) {
  float e = __expf(2.0f * x);
  return 1.0f - 2.0f / (e + 1.0f);
}

// ---------------------------------------------------------------------------
__global__ void prep_kernel(const float* __restrict__ w, float* __restrict__ wT,
                            const float* __restrict__ gw, const float* __restrict__ aw,
                            const float* __restrict__ dw, const float* __restrict__ uw,
                            float* __restrict__ wpack, float* __restrict__ acc3,
                            unsigned* __restrict__ cnt) {
  const int g = blockIdx.x * 256 + threadIdx.x;
  if (g < 131072) {
    const int c = g >> 7, k = g & 127;
    wT[k * 1024 + c] = w[g];
  }
  if (g < 1280) {
    const int f = g / 160, r = g % 160, ci = r >> 4, k = r & 15;
    float v = 0.f;
    if (ci < 9) {
      if (k < 5)       v = gw[(f * 9 + ci) * 5 + k];
      else if (k < 10) v = aw[(f * 9 + ci) * 5 + (k - 5)];
      else if (k < 15) v = dw[(f * 9 + ci) * 5 + (k - 10)];
    } else {
      if (k < 5)       v = uw[f * 5 + k];
    }
    wpack[g] = v;
  }
  if (g < (int)ACC_SZ) acc3[g] = 0.f;
  if (g < 1024) cnt[g] = 0u;
}

// ---------------------------------------------------------------------------
__global__ void __launch_bounds__(256) xr_kernel(const float* __restrict__ x,
                                                 const float* __restrict__ wT,
                                                 float* __restrict__ XR) {
  const int tb0 = blockIdx.x * 16;
  const int c0  = threadIdx.x * 4;
  float4 acc[16];
#pragma unroll
  for (int j = 0; j < 16; ++j) acc[j] = make_float4(0.f, 0.f, 0.f, 0.f);
#pragma unroll 4
  for (int k = 0; k < 128; ++k) {
    const float4 wv = *(const float4*)(wT + (size_t)k * 1024 + c0);
#pragma unroll
    for (int j = 0; j < 16; ++j) {
      const int tb = tb0 + j;
      const float xs = x[(size_t)(tb & 31) * 16384 + (size_t)(tb >> 5) * 128 + k];
      acc[j].x = fmaf(xs, wv.x, acc[j].x);
      acc[j].y = fmaf(xs, wv.y, acc[j].y);
      acc[j].z = fmaf(xs, wv.z, acc[j].z);
      acc[j].w = fmaf(xs, wv.w, acc[j].w);
    }
  }
#pragma unroll
  for (int j = 0; j < 16; ++j) {
    float* row = XR + (size_t)(tb0 + j) * PROW;
    *(float4*)(row + 4 + c0) = acc[j];
    if (threadIdx.x == 0)   { row[0] = row[1] = row[2] = row[3] = 0.f; }
    if (threadIdx.x == 255) { row[1028] = row[1029] = row[1030] = row[1031] = 0.f; }
  }
}

// ---------------------------------------------------------------------------
// scan: block=(bb,cc); wave=feature f; lane owns cols {2l, 2l+1} of chunk.
// ---------------------------------------------------------------------------
__global__ void __launch_bounds__(NTHR) scan_kernel(
    const float* __restrict__ XR, const float* __restrict__ wpack,
    float* acc3, float* slots2, unsigned* cnt,
    const float* __restrict__ s_in, const float* __restrict__ n_in,
    const float* __restrict__ d_in, const float* __restrict__ h_in,
    const float* __restrict__ am_in,
    const float* __restrict__ ggm, const float* __restrict__ gbt,
    const float* __restrict__ ugm, const float* __restrict__ ubt,
    const float* __restrict__ agm, const float* __restrict__ abt,
    const float* __restrict__ dgm, const float* __restrict__ dbt,
    float* __restrict__ out)
{
  const int bb   = (int)blockIdx.x >> 3;   // batch
  const int cc   = (int)blockIdx.x & 7;    // column chunk (128 cols)
  const int tid  = (int)threadIdx.x;
  const int w    = tid >> 6;               // wave == feature
  const int lane = tid & 63;
  const int fu   = __builtin_amdgcn_readfirstlane(w);
  const float* __restrict__ wpk = wpack + fu * 160;   // [ci][16], wave-uniform

  const int c0   = 2 * lane;               // chunk-local col
  const int gc0  = cc * 128 + c0;          // global col
  const int cellbase = bb * 8192 + w * 1024 + gc0;
  const int rep  = (int)blockIdx.x & 3;    // accumulator replica

  const float ggamma = ggm[fu], gbeta = gbt[fu];
  const float ugamma = ugm[fu], ubeta = ubt[fu];
  const float agamma = agm[fu], abeta = abt[fu];
  const float dgamma = dgm[fu], dbeta = dbt[fu];

  __shared__ float hl[8][136];   // row: [2 zero][2 haloL][128 own][2 haloR][2 zero]

  // ---- own-col states (2 cells) + halo states (lanes 0-3, 1 cell each) ----
  float nst[2], dst[2], amst[2], hv[2];
  float hn = 0.f, hd = 0.f, ham = -1e38f;
  const int  hloc   = (lane < 2) ? (lane - 2) : (128 + (lane - 2)); // -2,-1,128,129
  const bool hvalid = (lane < 4) && ((lane < 2) ? (cc > 0) : (cc < 7));
  {
    const float2 n2 = *(const float2*)(n_in  + cellbase);
    const float2 d2 = *(const float2*)(d_in  + cellbase);
    const float2 a2 = *(const float2*)(am_in + cellbase);
    const float2 h2 = *(const float2*)(h_in  + cellbase);
    const float2 s2 = *(const float2*)(s_in  + cellbase);
    nst[0] = n2.x; nst[1] = n2.y;
    dst[0] = d2.x; dst[1] = d2.y;
    amst[0] = a2.x; amst[1] = a2.y;
    hv[0] = h2.x + fast_tanh(s2.x);
    hv[1] = h2.y + fast_tanh(s2.y);
    *(float2*)&hl[w][c0 + 4] = make_float2(hv[0], hv[1]);

    float hh0 = 0.f;
    if (hvalid) {
      const int gcell = bb * 8192 + w * 1024 + cc * 128 + hloc;
      hn  = n_in[gcell]; hd = d_in[gcell]; ham = am_in[gcell];
      hh0 = h_in[gcell] + fast_tanh(s_in[gcell]);
    }
    if (lane < 4) hl[w][hloc + 4] = hh0;
    if (lane >= 4 && lane < 8) {   // zero guard pads
      const int pidx = (lane == 4) ? 0 : (lane == 5) ? 1 : (lane == 6) ? 134 : 135;
      hl[w][pidx] = 0.f;
    }
  }
  __syncthreads();

  for (int t = 0; t < Tt; ++t) {
    const int p2 = t & 1;
    const int p3 = t % 3;

    // ---- phase A: conv over own 2 cols --------------------------------------
    float accg[2] = {0.f, 0.f}, acca[2] = {0.f, 0.f};
    float accd[2] = {0.f, 0.f}, accu[2] = {0.f, 0.f};

    // XR window first (global, latency hides under LDS convs)
    const float2* xr2 = (const float2*)(XR + (size_t)(t * Bb + bb) * PROW + 2 + gc0);
    const float2 xa = xr2[0], xb = xr2[1], xc = xr2[2];

#pragma unroll
    for (int r = 0; r < 8; ++r) {          // input channels 1..8 = h rows
      const float2 qa = *(const float2*)&hl[r][c0 + 2];
      const float2 qb = *(const float2*)&hl[r][c0 + 4];
      const float2 qc = *(const float2*)&hl[r][c0 + 6];
      const float w6[6] = {qa.x, qa.y, qb.x, qb.y, qc.x, qc.y};
      const float* wp = wpk + (r + 1) * 16;
#pragma unroll
      for (int kw = 0; kw < 5; ++kw) {
        const float wg = wp[kw], wa = wp[5 + kw], wd = wp[10 + kw];
#pragma unroll
        for (int j = 0; j < 2; ++j) {
          const float v = w6[j + kw];
          accg[j] = fmaf(v, wg, accg[j]);
          acca[j] = fmaf(v, wa, acca[j]);
          accd[j] = fmaf(v, wd, accd[j]);
        }
      }
    }
    {                                      // input channel 0 = xr (+ u conv)
      const float w6[6] = {xa.x, xa.y, xb.x, xb.y, xc.x, xc.y};
      const float* wp = wpk;
      const float* wu = wpk + 144;
#pragma unroll
      for (int kw = 0; kw < 5; ++kw) {
        const float wg = wp[kw], wa = wp[5 + kw], wd = wp[10 + kw], wv = wu[kw];
#pragma unroll
        for (int j = 0; j < 2; ++j) {
          const float v = w6[j + kw];
          accg[j] = fmaf(v, wg, accg[j]);
          acca[j] = fmaf(v, wa, acca[j]);
          accd[j] = fmaf(v, wd, accd[j]);
          accu[j] = fmaf(v, wv, accu[j]);
        }
      }
    }

    // ---- BN partials: full-wave reduce, lanes 0-7 atomicAdd -----------------
    {
      float ps[8];
      ps[0] = accg[0] + accg[1]; ps[1] = fmaf(accg[0], accg[0], accg[1] * accg[1]);
      ps[2] = acca[0] + acca[1]; ps[3] = fmaf(acca[0], acca[0], acca[1] * acca[1]);
      ps[4] = accd[0] + accd[1]; ps[5] = fmaf(accd[0], accd[0], accd[1] * accd[1]);
      ps[6] = accu[0] + accu[1]; ps[7] = fmaf(accu[0], accu[0], accu[1] * accu[1]);
#pragma unroll
      for (int k = 0; k < 8; ++k) {
        float v = ps[k];
#pragma unroll
        for (int m = 1; m <= 32; m <<= 1) v += __shfl_xor(v, m);
        ps[k] = v;
      }
      float myv = ps[0];
#pragma unroll
      for (int k = 1; k < 8; ++k) if (lane == k) myv = ps[k];
      if (lane < 8)
        __hip_atomic_fetch_add(acc3 + p3 * 8192 + rep * 2048 + (w * 8 + lane) * 32,
                               myv, __ATOMIC_RELAXED, __HIP_MEMORY_SCOPE_AGENT);
    }

    // ---- export raw conv outputs at boundary cols ---------------------------
    if (lane == 0 || lane == 63) {
      const int side = lane ? 1 : 0;
      float* bs = slots2 + ((((size_t)p2 * 32 + bb) * 8 + cc) * 2 + side) * 64 + w * 8;
      __hip_atomic_store(bs + 0, accg[0], __ATOMIC_RELAXED, __HIP_MEMORY_SCOPE_AGENT);
      __hip_atomic_store(bs + 1, accg[1], __ATOMIC_RELAXED, __HIP_MEMORY_SCOPE_AGENT);
      __hip_atomic_store(bs + 2, acca[0], __ATOMIC_RELAXED, __HIP_MEMORY_SCOPE_AGENT);
      __hip_atomic_store(bs + 3, acca[1], __ATOMIC_RELAXED, __HIP_MEMORY_SCOPE_AGENT);
      __hip_atomic_store(bs + 4, accd[0], __ATOMIC_RELAXED, __HIP_MEMORY_SCOPE_AGENT);
      __hip_atomic_store(bs + 5, accd[1], __ATOMIC_RELAXED, __HIP_MEMORY_SCOPE_AGENT);
      __hip_atomic_store(bs + 6, accu[0], __ATOMIC_RELAXED, __HIP_MEMORY_SCOPE_AGENT);
      __hip_atomic_store(bs + 7, accu[1], __ATOMIC_RELAXED, __HIP_MEMORY_SCOPE_AGENT);
    }

    // ---- single global sync (16 leaves x 16 blocks, monotonic counters) -----
    asm volatile("s_waitcnt vmcnt(0)" ::: "memory");
    __syncthreads();
    if (tid == 0) {
      unsigned* leaf = cnt + ((blockIdx.x >> 4) * 32);
      unsigned* root = cnt + 16 * 32;
      unsigned* gen  = cnt + 17 * 32;
      const unsigned tgt = (unsigned)(t + 1);
      const unsigned old =
          __hip_atomic_fetch_add(leaf, 1u, __ATOMIC_RELAXED, __HIP_MEMORY_SCOPE_AGENT);
      if (old == 16u * tgt - 1u) {
        const unsigned old2 =
            __hip_atomic_fetch_add(root, 1u, __ATOMIC_RELAXED, __HIP_MEMORY_SCOPE_AGENT);
        if (old2 == 16u * tgt - 1u)
          __hip_atomic_store(gen, tgt, __ATOMIC_RELAXED, __HIP_MEMORY_SCOPE_AGENT);
      }
      while (__hip_atomic_load(gen, __ATOMIC_RELAXED, __HIP_MEMORY_SCOPE_AGENT) < tgt)
        __builtin_amdgcn_s_sleep(1);
    }
    __syncthreads();

    // ---- stats readback (4 replicas) + broadcast ----------------------------
    float st[8];
    {
      float sv = 0.f;
      if (lane < 8) {
        const float* ap = acc3 + p3 * 8192 + (w * 8 + lane) * 32;
#pragma unroll
        for (int r = 0; r < 4; ++r)
          sv += __hip_atomic_load(ap + r * 2048, __ATOMIC_RELAXED, __HIP_MEMORY_SCOPE_AGENT);
      }
#pragma unroll
      for (int k = 0; k < 8; ++k) st[k] = __shfl(sv, k);
    }
    if (blockIdx.x == 0 && tid < 256)   // zero parity (t+2)%3 for reuse at t+2
      __hip_atomic_store(acc3 + ((t + 2) % 3) * 8192 + tid * 32, 0.f,
                         __ATOMIC_RELAXED, __HIP_MEMORY_SCOPE_AGENT);

    const float mg = st[0] * INV_N; const float vg = fmaf(-mg, mg, st[1] * INV_N);
    const float sg = ggamma * rsqrtf(vg + EPSf); const float og = fmaf(-mg, sg, gbeta);
    const float ma = st[2] * INV_N; const float va = fmaf(-ma, ma, st[3] * INV_N);
    const float sa = agamma * rsqrtf(va + EPSf); const float oa = fmaf(-ma, sa, abeta);
    const float md = st[4] * INV_N; const float vd = fmaf(-md, md, st[5] * INV_N);
    const float sd = dgamma * rsqrtf(vd + EPSf); const float od = fmaf(-md, sd, dbeta);
    const float mu = st[6] * INV_N; const float vu = fmaf(-mu, mu, st[7] * INV_N);
    const float su = ugamma * rsqrtf(vu + EPSf); const float ou = fmaf(-mu, su, ubeta);

    // ---- phase B: own cells -------------------------------------------------
#pragma unroll
    for (int j = 0; j < 2; ++j) {
      const float gb = fmaf(accg[j], sg, og);
      const float ab = fmaf(acca[j], sa, oa);
      const float db = fmaf(accd[j], sd, od);
      const float ub = fmaf(accu[j], su, ou);
      const float dec = 1.0f / (1.0f + __expf(-db));
      const float ed  = __expf(-dec);
      const float z   = ub * fast_tanh(gb);
      const float anew = fmaxf(amst[j] * ed, ab);
      const float e1 = __expf(amst[j] - anew);
      const float e2 = __expf(ab - anew);
      const float ede1 = ed * e1;
      nst[j]  = fmaf(nst[j], ede1, z * e2);
      dst[j]  = fmaf(dst[j], ede1, e2);
      amst[j] = anew;
      hv[j]   = fast_tanh(nst[j] / dst[j]);
    }
    *(float2*)&hl[w][c0 + 4] = make_float2(hv[0], hv[1]);

    // ---- phase B: replicated halo cells (lanes 0-3) -------------------------
    if (lane < 4) {
      float hres = 0.f;
      if (hvalid) {
        const int ncc  = (lane < 2) ? (cc - 1) : (cc + 1);
        const int nsid = (lane < 2) ? 1 : 0;
        const float* nb =
            slots2 + ((((size_t)p2 * 32 + bb) * 8 + ncc) * 2 + nsid) * 64 + w * 8 + (lane & 1);
        const float graw = __hip_atomic_load(nb + 0, __ATOMIC_RELAXED, __HIP_MEMORY_SCOPE_AGENT);
        const float araw = __hip_atomic_load(nb + 2, __ATOMIC_RELAXED, __HIP_MEMORY_SCOPE_AGENT);
        const float draw = __hip_atomic_load(nb + 4, __ATOMIC_RELAXED, __HIP_MEMORY_SCOPE_AGENT);
        const float uraw = __hip_atomic_load(nb + 6, __ATOMIC_RELAXED, __HIP_MEMORY_SCOPE_AGENT);
        const float gb = fmaf(graw, sg, og);
        const float ab = fmaf(araw, sa, oa);
        const float db = fmaf(draw, sd, od);
        const float ub = fmaf(uraw, su, ou);
        const float dec = 1.0f / (1.0f + __expf(-db));
        const float ed  = __expf(-dec);
        const float z   = ub * fast_tanh(gb);
        const float anew = fmaxf(ham * ed, ab);
        const float e1 = __expf(ham - anew);
        const float e2 = __expf(ab - anew);
        const float ede1 = ed * e1;
        hn  = fmaf(hn, ede1, z * e2);
        hd  = fmaf(hd, ede1, e2);
        ham = anew;
        hres = fast_tanh(hn / hd);
      }
      hl[w][hloc + 4] = hres;
    }
    __syncthreads();
  }

  // ---- final outputs --------------------------------------------------------
  {
    const float2 s2 = *(const float2*)(s_in + cellbase);
    *(float2*)(out + OUT_S  + cellbase) = s2;
    *(float2*)(out + OUT_N  + cellbase) = make_float2(nst[0], nst[1]);
    *(float2*)(out + OUT_D  + cellbase) = make_float2(dst[0], dst[1]);
    *(float2*)(out + OUT_H  + cellbase) = make_float2(hv[0], hv[1]);
    *(float2*)(out + OUT_AM + cellbase) = make_float2(amst[0], amst[1]);
  }
}

// ---------------------------------------------------------------------------
__global__ void __launch_bounds__(256) out_kernel(const float* __restrict__ outH,
                                                  const float* __restrict__ ow,
                                                  const float* __restrict__ ob,
                                                  float* __restrict__ out) {
  const int g = blockIdx.x * 256 + threadIdx.x;  // 32000 threads
  const int o = g >> 5;
  const int b = g & 31;
  const float* hp = outH + (size_t)b * 8192;
  const float* wp = ow + (size_t)o * 8192;
  float acc = 0.f;
#pragma unroll 8
  for (int c = 0; c < 8192; c += 4) {
    const float4 hv4 = *(const float4*)(hp + c);
    const float4 wv4 = *(const float4*)(wp + c);
    acc = fmaf(hv4.x, wv4.x, acc);
    acc = fmaf(hv4.y, wv4.y, acc);
    acc = fmaf(hv4.z, wv4.z, acc);
    acc = fmaf(hv4.w, wv4.w, acc);
  }
  out[b * 1000 + o] = acc + ob[o];
}

// ---------------------------------------------------------------------------
extern "C" void kernel_launch(void* const* d_in, const int* in_sizes, int n_in,
                              void* d_out, int out_size, void* d_ws, size_t ws_size,
                              hipStream_t stream) {
  (void)in_sizes; (void)n_in; (void)out_size; (void)ws_size;
  const float* x   = (const float*)d_in[0];
  const float* s   = (const float*)d_in[1];
  const float* n_  = (const float*)d_in[2];
  const float* dd  = (const float*)d_in[3];
  const float* h   = (const float*)d_in[4];
  const float* am  = (const float*)d_in[5];
  const float* xrw = (const float*)d_in[6];
  const float* gw  = (const float*)d_in[7];
  const float* ggm = (const float*)d_in[9];
  const float* gbt = (const float*)d_in[10];
  const float* uw  = (const float*)d_in[11];
  const float* ugm = (const float*)d_in[13];
  const float* ubt = (const float*)d_in[14];
  const float* aw  = (const float*)d_in[15];
  const float* agm = (const float*)d_in[17];
  const float* abt = (const float*)d_in[18];
  const float* dw  = (const float*)d_in[19];
  const float* dgm = (const float*)d_in[21];
  const float* dbt = (const float*)d_in[22];
  const float* ow  = (const float*)d_in[23];
  const float* ob  = (const float*)d_in[24];
  float* out = (float*)d_out;
  float* ws  = (float*)d_ws;

  float* XR     = ws + XR_OFF;
  float* wT     = ws + WT_OFF;
  float* wpack  = ws + WPK_OFF;
  float* acc3   = ws + ACC_OFF;
  float* slots2 = ws + SL2_OFF;
  unsigned* cnt = (unsigned*)(ws + CNT_OFF);

  prep_kernel<<<dim3(512), dim3(256), 0, stream>>>(xrw, wT, gw, aw, dw, uw, wpack, acc3, cnt);
  xr_kernel<<<dim3(256), dim3(256), 0, stream>>>(x, wT, XR);

  void* args[] = { &XR, &wpack, &acc3, &slots2, &cnt, &s, &n_, &dd, &h, &am,
                   &ggm, &gbt, &ugm, &ubt, &agm, &abt, &dgm, &dbt, &out };
  hipError_t err = hipLaunchCooperativeKernel((void*)scan_kernel, dim3(NBLK), dim3(NTHR),
                                              args, 0, stream);
  if (err != hipSuccess) {
    scan_kernel<<<dim3(NBLK), dim3(NTHR), 0, stream>>>(XR, wpack, acc3, slots2, cnt,
                                                       s, n_, dd, h, am,
                                                       ggm, gbt, ugm, ubt, agm, abt,
                                                       dgm, dbt, out);
  }

  out_kernel<<<dim3(125), dim3(256), 0, stream>>>(out + OUT_H, ow, ob, out);
}